// Round 1
// baseline (739.260 us; speedup 1.0000x reference)
//
#include <hip/hip_runtime.h>
#include <hip/hip_bf16.h>

#define B_      32
#define HID_    2048
#define INNER_  4096
#define NH_     8
#define HEAD_   512
#define CAP_    30.0f

typedef short short8 __attribute__((ext_vector_type(8)));
typedef float f32x4 __attribute__((ext_vector_type(4)));

static __device__ __forceinline__ unsigned short f2bf(float f) {
    unsigned int u = __float_as_uint(f);
    u = (u + 0x7fffu + ((u >> 16) & 1u)) >> 16;   // RNE
    return (unsigned short)u;
}

static __device__ __forceinline__ float sigm(float x) { return 1.0f / (1.0f + expf(-x)); }
static __device__ __forceinline__ float silu(float x) { return x * sigm(x); }

// ---------------------------------------------------------------------------
// RMSNorm: xn = x * rsqrt(mean(x^2)+eps) * rms_w      (B blocks)
// ---------------------------------------------------------------------------
__global__ void k_rms(const float* __restrict__ x, const float* __restrict__ rms_w,
                      float* __restrict__ xn) {
    const int b = blockIdx.x, t = threadIdx.x;
    __shared__ float red[4];
    const float* xr = x + b * HID_;
    float s = 0.f;
    for (int i = t; i < HID_; i += 256) { float v = xr[i]; s += v * v; }
    for (int off = 32; off; off >>= 1) s += __shfl_down(s, off, 64);
    if ((t & 63) == 0) red[t >> 6] = s;
    __syncthreads();
    const float scale = rsqrtf((red[0] + red[1] + red[2] + red[3]) / (float)HID_ + 1e-6f);
    float* xo = xn + b * HID_;
    for (int i = t; i < HID_; i += 256) xo[i] = xr[i] * scale * rms_w[i];
}

// ---------------------------------------------------------------------------
// Skinny GEMM: C[32][N] (+)= A[32][K] @ W[N][K]^T   via bf16 MFMA 16x16x32.
// f32 loaded from global, converted to bf16 while staging into LDS.
// Split-K over gridDim.y with f32 atomicAdd (C must be pre-initialized).
// block=256 (4 waves); block tile = 32 rows x 64 cols; K-tile = 128.
// ---------------------------------------------------------------------------
__global__ void k_gemm(const float* __restrict__ A, const float* __restrict__ W,
                       float* __restrict__ C, int N, int K, int Kper) {
    __shared__ unsigned short Al[32][136];   // pad 8 -> row stride 272 B (16B-mult)
    __shared__ unsigned short Wl[64][136];
    const int tid  = threadIdx.x;
    const int lane = tid & 63;
    const int wave = tid >> 6;
    const int quad = lane >> 4;
    const int l16  = lane & 15;
    const int oBlk = blockIdx.x * 64;
    const int k0s  = blockIdx.y * Kper;
    const int ntiles = Kper >> 7;

    f32x4 acc0 = {0.f, 0.f, 0.f, 0.f};
    f32x4 acc1 = {0.f, 0.f, 0.f, 0.f};

    for (int kt = 0; kt < ntiles; ++kt) {
        const int k0 = k0s + kt * 128;
        // stage A tile (32x128): 1024 float4s
        for (int i = tid; i < 1024; i += 256) {
            const int r = i >> 5, c = i & 31;
            const float4 f = *(const float4*)(A + r * K + k0 + c * 4);
            ushort4 u; u.x = f2bf(f.x); u.y = f2bf(f.y); u.z = f2bf(f.z); u.w = f2bf(f.w);
            *(ushort4*)&Al[r][c * 4] = u;
        }
        // stage W tile (64x128): 2048 float4s
        for (int i = tid; i < 2048; i += 256) {
            const int r = i >> 5, c = i & 31;
            const float4 f = *(const float4*)(W + (size_t)(oBlk + r) * K + k0 + c * 4);
            ushort4 u; u.x = f2bf(f.x); u.y = f2bf(f.y); u.z = f2bf(f.z); u.w = f2bf(f.w);
            *(ushort4*)&Wl[r][c * 4] = u;
        }
        __syncthreads();
        #pragma unroll
        for (int ks = 0; ks < 4; ++ks) {
            const int kk = ks * 32 + quad * 8;
            const short8 a0 = *(const short8*)&Al[l16][kk];
            const short8 a1 = *(const short8*)&Al[16 + l16][kk];
            const short8 wf = *(const short8*)&Wl[wave * 16 + l16][kk];
            acc0 = __builtin_amdgcn_mfma_f32_16x16x32_bf16(a0, wf, acc0, 0, 0, 0);
            acc1 = __builtin_amdgcn_mfma_f32_16x16x32_bf16(a1, wf, acc1, 0, 0, 0);
        }
        __syncthreads();
    }
    // C/D layout: col = lane&15, row = quad*4 + reg   [m89/m91 verified]
    const int o = oBlk + wave * 16 + l16;
    #pragma unroll
    for (int r = 0; r < 4; ++r) {
        const int b0 = quad * 4 + r;
        atomicAdd(&C[(size_t)b0 * N + o], acc0[r]);
        atomicAdd(&C[(size_t)(16 + b0) * N + o], acc1[r]);
    }
}

// ---------------------------------------------------------------------------
// Causal conv (K=4) + silu; emits new_conv_state.
// ---------------------------------------------------------------------------
__global__ void k_conv(const float* __restrict__ xm, const float* __restrict__ conv_state,
                       const float* __restrict__ conv_w, const float* __restrict__ conv_b,
                       float* __restrict__ xmc, float* __restrict__ ncs_out) {
    const int idx = blockIdx.x * 256 + threadIdx.x;   // b*INNER + c
    if (idx >= B_ * INNER_) return;
    const int c = idx & (INNER_ - 1);
    const float* cs = conv_state + (size_t)idx * 3;
    const float c0 = cs[0], c1 = cs[1], c2 = cs[2];
    const float xv = xm[idx];
    const float* w = conv_w + c * 4;
    const float conv = c0 * w[0] + c1 * w[1] + c2 * w[2] + xv * w[3] + conv_b[c];
    xmc[idx] = silu(conv);
    float* no = ncs_out + (size_t)idx * 3;
    no[0] = c1; no[1] = c2; no[2] = xv;
}

// ---------------------------------------------------------------------------
// Input/forget gates: one block per (b,h); dot over 3*INNER.
// ---------------------------------------------------------------------------
__global__ void k_gates(const float* __restrict__ qkv, const float* __restrict__ Wi,
                        const float* __restrict__ bi, const float* __restrict__ Wf,
                        const float* __restrict__ bfv, const float* __restrict__ max_state,
                        float* __restrict__ i_gate, float* __restrict__ f_gate,
                        float* __restrict__ max_new) {
    const int bh = blockIdx.x, b = bh >> 3, h = bh & 7, t = threadIdx.x;
    const float* q  = qkv + (size_t)b * (3 * INNER_);
    const float* wi = Wi + (size_t)h * (3 * INNER_);
    const float* wf = Wf + (size_t)h * (3 * INNER_);
    float si = 0.f, sf = 0.f;
    for (int j = t; j < 3 * INNER_; j += 256) {
        const float v = q[j];
        si += v * wi[j];
        sf += v * wf[j];
    }
    __shared__ float r1[4], r2[4];
    for (int off = 32; off; off >>= 1) {
        si += __shfl_down(si, off, 64);
        sf += __shfl_down(sf, off, 64);
    }
    if ((t & 63) == 0) { r1[t >> 6] = si; r2[t >> 6] = sf; }
    __syncthreads();
    if (t == 0) {
        float ig = r1[0] + r1[1] + r1[2] + r1[3] + bi[h];
        float fg = r2[0] + r2[1] + r2[2] + r2[3] + bfv[h];
        ig = CAP_ * tanhf(ig / CAP_);
        fg = CAP_ * tanhf(fg / CAP_);
        const float logf_ = (fg >= 0.f) ? -log1pf(expf(-fg)) : (fg - log1pf(expf(fg)));
        const float ms = max_state[bh];
        const float mn = fmaxf(ig, ms + logf_);
        max_new[bh] = mn;
        i_gate[bh] = expf(ig - mn);
        f_gate[bh] = expf(logf_ + ms - mn);
    }
}

// ---------------------------------------------------------------------------
// Fused cell update + numer + norm_new + qn + groupnorm + h epilogue.
// One block per (b,h). 256 threads; cell row traffic is float4-coalesced.
// ---------------------------------------------------------------------------
__global__ void k_cell(const float* __restrict__ qkv, const float* __restrict__ i_gate,
                       const float* __restrict__ f_gate, const float* __restrict__ max_new,
                       const float* __restrict__ cell_state, const float* __restrict__ norm_state,
                       const float* __restrict__ gn_w, const float* __restrict__ gn_b,
                       const float* __restrict__ skip_w, const float* __restrict__ xmc,
                       const float* __restrict__ x_gate,
                       float* __restrict__ cell_out, float* __restrict__ norm_out,
                       float* __restrict__ h_out) {
    const int bh = blockIdx.x, b = bh >> 3, h = bh & 7, t = threadIdx.x;
    __shared__ float q_l[HEAD_], ik_l[HEAD_], nsum[HEAD_];
    __shared__ float redA[4], redB[4];
    const float i_g = i_gate[bh], f_g = f_gate[bh], mx = max_new[bh];
    const float rs = 0.044194173824159216f;   // 1/sqrt(512)
    const float* qr = qkv + (size_t)b * (3 * INNER_) + h * HEAD_;
    const float* kr = qr + INNER_;
    const float* vr = qr + 2 * INNER_;
    const float* ns = norm_state + (size_t)bh * HEAD_;

    // phase 1: q/ik into LDS, norm_new, qn partial
    float qn = 0.f;
    for (int d = t; d < HEAD_; d += 256) {
        const float qv = qr[d];
        const float ik = i_g * (kr[d] * rs);
        q_l[d] = qv; ik_l[d] = ik;
        const float nn = f_g * ns[d] + ik;
        norm_out[(size_t)bh * HEAD_ + d] = nn;
        qn += qv * nn;
    }
    for (int off = 32; off; off >>= 1) qn += __shfl_down(qn, off, 64);
    if ((t & 63) == 0) redA[t >> 6] = qn;
    __syncthreads();
    qn = redA[0] + redA[1] + redA[2] + redA[3];
    const float denom = fmaxf(fabsf(qn), expf(-mx)) + 1e-6f;

    // phase 2: cell update + numer (half-split over d)
    const int half = t >> 7;
    const int e0 = (t & 127) * 4;
    const float4 v4 = *(const float4*)(vr + e0);
    float4 num = {0.f, 0.f, 0.f, 0.f};
    const float* cin = cell_state + (size_t)bh * (HEAD_ * HEAD_);
    float* cout = cell_out + (size_t)bh * (HEAD_ * HEAD_);
    const int d0 = half * 256;
    for (int d = d0; d < d0 + 256; ++d) {
        const float4 c4 = *(const float4*)(cin + (size_t)d * HEAD_ + e0);
        const float ik = ik_l[d], qv = q_l[d];
        float4 cn;
        cn.x = f_g * c4.x + ik * v4.x;
        cn.y = f_g * c4.y + ik * v4.y;
        cn.z = f_g * c4.z + ik * v4.z;
        cn.w = f_g * c4.w + ik * v4.w;
        *(float4*)(cout + (size_t)d * HEAD_ + e0) = cn;
        num.x += qv * cn.x; num.y += qv * cn.y; num.z += qv * cn.z; num.w += qv * cn.w;
    }
    __syncthreads();
    if (half == 0) { nsum[e0] = num.x; nsum[e0+1] = num.y; nsum[e0+2] = num.z; nsum[e0+3] = num.w; }
    __syncthreads();
    if (half == 1) { nsum[e0] += num.x; nsum[e0+1] += num.y; nsum[e0+2] += num.z; nsum[e0+3] += num.w; }
    __syncthreads();

    // phase 3: groupnorm stats over HEAD
    float s = 0.f, s2 = 0.f;
    for (int e = t; e < HEAD_; e += 256) {
        const float o = nsum[e] / denom;
        s += o; s2 += o * o;
    }
    for (int off = 32; off; off >>= 1) {
        s  += __shfl_down(s, off, 64);
        s2 += __shfl_down(s2, off, 64);
    }
    if ((t & 63) == 0) { redA[t >> 6] = s; redB[t >> 6] = s2; }
    __syncthreads();
    const float mu  = (redA[0] + redA[1] + redA[2] + redA[3]) / (float)HEAD_;
    const float ex2 = (redB[0] + redB[1] + redB[2] + redB[3]) / (float)HEAD_;
    const float inv = rsqrtf(fmaxf(ex2 - mu * mu, 0.f) + 1e-5f);

    // phase 4: gn scale/shift + skip + gate -> h
    for (int e = t; e < HEAD_; e += 256) {
        const int i = h * HEAD_ + e;
        const float og = (nsum[e] / denom - mu) * inv * gn_w[i] + gn_b[i];
        const float xg = x_gate[(size_t)b * INNER_ + i];
        const float hv = (og + skip_w[i] * xmc[(size_t)b * INNER_ + i]) * silu(xg);
        h_out[(size_t)b * INNER_ + i] = hv;
    }
}

// ---------------------------------------------------------------------------
extern "C" void kernel_launch(void* const* d_in, const int* in_sizes, int n_in,
                              void* d_out, int out_size, void* d_ws, size_t ws_size,
                              hipStream_t stream) {
    const float* x          = (const float*)d_in[0];
    const float* conv_state = (const float*)d_in[1];
    const float* cell_state = (const float*)d_in[2];
    const float* norm_state = (const float*)d_in[3];
    const float* max_state  = (const float*)d_in[4];
    const float* rms_w      = (const float*)d_in[5];
    const float* Wx         = (const float*)d_in[6];
    const float* Wg         = (const float*)d_in[7];
    const float* Wqkv       = (const float*)d_in[8];
    const float* conv_w     = (const float*)d_in[9];
    const float* conv_b     = (const float*)d_in[10];
    const float* Wi         = (const float*)d_in[11];
    const float* bi         = (const float*)d_in[12];
    const float* Wf         = (const float*)d_in[13];
    const float* bfv        = (const float*)d_in[14];
    const float* gn_w       = (const float*)d_in[15];
    const float* gn_b       = (const float*)d_in[16];
    const float* Wdown      = (const float*)d_in[17];
    const float* skip_w     = (const float*)d_in[18];

    float* out = (float*)d_out;
    float* y_out    = out;                                   // 32*2048
    float* ncs_out  = y_out + B_ * HID_;                     // 32*4096*3
    float* cell_out = ncs_out + (size_t)B_ * INNER_ * 3;     // 32*8*512*512
    float* norm_out = cell_out + (size_t)B_ * NH_ * HEAD_ * HEAD_;
    float* max_out  = norm_out + (size_t)B_ * NH_ * HEAD_;

    float* w = (float*)d_ws;
    float* xn      = w;                          // 65536
    float* xmc     = xn + B_ * HID_;             // 131072
    float* h_ws    = xmc + B_ * INNER_;          // 131072
    float* i_g_ws  = h_ws + B_ * INNER_;         // 256
    float* f_g_ws  = i_g_ws + B_ * NH_;          // 256
    float* x_mlstm = f_g_ws + B_ * NH_;          // 131072  (zeroed, atomic target)
    float* x_gate  = x_mlstm + B_ * INNER_;      // 131072  (zeroed, atomic target)
    float* qkv     = x_gate + B_ * INNER_;       // 393216  (zeroed, atomic target)

    // zero the atomic GEMM targets in one memset; y pre-init = skip (x)
    hipMemsetAsync(x_mlstm, 0, (size_t)(2 * B_ * INNER_ + B_ * 3 * INNER_) * 4, stream);
    hipMemcpyAsync(y_out, x, (size_t)B_ * HID_ * 4, hipMemcpyDeviceToDevice, stream);

    k_rms<<<B_, 256, 0, stream>>>(x, rms_w, xn);

    k_gemm<<<dim3(INNER_ / 64, 8), 256, 0, stream>>>(xn, Wx, x_mlstm, INNER_, HID_, HID_ / 8);
    k_gemm<<<dim3(INNER_ / 64, 8), 256, 0, stream>>>(xn, Wg, x_gate, INNER_, HID_, HID_ / 8);

    k_conv<<<(B_ * INNER_) / 256, 256, 0, stream>>>(x_mlstm, conv_state, conv_w, conv_b,
                                                    xmc, ncs_out);

    k_gemm<<<dim3(3 * INNER_ / 64, 4), 256, 0, stream>>>(xmc, Wqkv, qkv,
                                                         3 * INNER_, INNER_, INNER_ / 4);

    k_gates<<<B_ * NH_, 256, 0, stream>>>(qkv, Wi, bi, Wf, bfv, max_state,
                                          i_g_ws, f_g_ws, max_out);

    k_cell<<<B_ * NH_, 256, 0, stream>>>(qkv, i_g_ws, f_g_ws, max_out, cell_state, norm_state,
                                         gn_w, gn_b, skip_w, xmc, x_gate,
                                         cell_out, norm_out, h_ws);

    k_gemm<<<dim3(HID_ / 64, 8), 256, 0, stream>>>(h_ws, Wdown, y_out, HID_, INNER_, INNER_ / 8);
}

// Round 2
// 718.843 us; speedup vs baseline: 1.0284x; 1.0284x over previous
//
#include <hip/hip_runtime.h>
#include <hip/hip_bf16.h>

#define B_      32
#define HID_    2048
#define INNER_  4096
#define NH_     8
#define HEAD_   512
#define CAP_    30.0f
#define DCH_    64          // d-rows per cell-stream block

typedef short short8 __attribute__((ext_vector_type(8)));
typedef float f32x4 __attribute__((ext_vector_type(4)));

static __device__ __forceinline__ unsigned short f2bf(float f) {
    unsigned int u = __float_as_uint(f);
    u = (u + 0x7fffu + ((u >> 16) & 1u)) >> 16;   // RNE
    return (unsigned short)u;
}

static __device__ __forceinline__ float sigm(float x) { return 1.0f / (1.0f + expf(-x)); }
static __device__ __forceinline__ float silu(float x) { return x * sigm(x); }

// ---------------------------------------------------------------------------
// RMSNorm: xn = x * rsqrt(mean(x^2)+eps) * rms_w      (B blocks)
// ---------------------------------------------------------------------------
__global__ void k_rms(const float* __restrict__ x, const float* __restrict__ rms_w,
                      float* __restrict__ xn) {
    const int b = blockIdx.x, t = threadIdx.x;
    __shared__ float red[4];
    const float* xr = x + b * HID_;
    float s = 0.f;
    for (int i = t; i < HID_; i += 256) { float v = xr[i]; s += v * v; }
    for (int off = 32; off; off >>= 1) s += __shfl_down(s, off, 64);
    if ((t & 63) == 0) red[t >> 6] = s;
    __syncthreads();
    const float scale = rsqrtf((red[0] + red[1] + red[2] + red[3]) / (float)HID_ + 1e-6f);
    float* xo = xn + b * HID_;
    for (int i = t; i < HID_; i += 256) xo[i] = xr[i] * scale * rms_w[i];
}

// ---------------------------------------------------------------------------
// Skinny GEMM: C[32][N] (+)= A[32][K] @ W[N][K]^T   via bf16 MFMA 16x16x32.
// Split-K over gridDim.y with f32 atomicAdd (C pre-zeroed).
// ---------------------------------------------------------------------------
__global__ __launch_bounds__(256) void k_gemm(const float* __restrict__ A,
                       const float* __restrict__ W,
                       float* __restrict__ C, int N, int K, int Kper) {
    __shared__ unsigned short Al[32][136];
    __shared__ unsigned short Wl[64][136];
    const int tid  = threadIdx.x;
    const int lane = tid & 63;
    const int wave = tid >> 6;
    const int quad = lane >> 4;
    const int l16  = lane & 15;
    const int oBlk = blockIdx.x * 64;
    const int k0s  = blockIdx.y * Kper;
    const int ntiles = Kper >> 7;

    f32x4 acc0 = {0.f, 0.f, 0.f, 0.f};
    f32x4 acc1 = {0.f, 0.f, 0.f, 0.f};

    for (int kt = 0; kt < ntiles; ++kt) {
        const int k0 = k0s + kt * 128;
        for (int i = tid; i < 1024; i += 256) {
            const int r = i >> 5, c = i & 31;
            const float4 f = *(const float4*)(A + r * K + k0 + c * 4);
            ushort4 u; u.x = f2bf(f.x); u.y = f2bf(f.y); u.z = f2bf(f.z); u.w = f2bf(f.w);
            *(ushort4*)&Al[r][c * 4] = u;
        }
        for (int i = tid; i < 2048; i += 256) {
            const int r = i >> 5, c = i & 31;
            const float4 f = *(const float4*)(W + (size_t)(oBlk + r) * K + k0 + c * 4);
            ushort4 u; u.x = f2bf(f.x); u.y = f2bf(f.y); u.z = f2bf(f.z); u.w = f2bf(f.w);
            *(ushort4*)&Wl[r][c * 4] = u;
        }
        __syncthreads();
        #pragma unroll
        for (int ks = 0; ks < 4; ++ks) {
            const int kk = ks * 32 + quad * 8;
            const short8 a0 = *(const short8*)&Al[l16][kk];
            const short8 a1 = *(const short8*)&Al[16 + l16][kk];
            const short8 wf = *(const short8*)&Wl[wave * 16 + l16][kk];
            acc0 = __builtin_amdgcn_mfma_f32_16x16x32_bf16(a0, wf, acc0, 0, 0, 0);
            acc1 = __builtin_amdgcn_mfma_f32_16x16x32_bf16(a1, wf, acc1, 0, 0, 0);
        }
        __syncthreads();
    }
    const int o = oBlk + wave * 16 + l16;
    #pragma unroll
    for (int r = 0; r < 4; ++r) {
        const int b0 = quad * 4 + r;
        atomicAdd(&C[(size_t)b0 * N + o], acc0[r]);
        atomicAdd(&C[(size_t)(16 + b0) * N + o], acc1[r]);
    }
}

// ---------------------------------------------------------------------------
// Causal conv (K=4) + silu; emits new_conv_state.
// ---------------------------------------------------------------------------
__global__ void k_conv(const float* __restrict__ xm, const float* __restrict__ conv_state,
                       const float* __restrict__ conv_w, const float* __restrict__ conv_b,
                       float* __restrict__ xmc, float* __restrict__ ncs_out) {
    const int idx = blockIdx.x * 256 + threadIdx.x;
    if (idx >= B_ * INNER_) return;
    const int c = idx & (INNER_ - 1);
    const float* cs = conv_state + (size_t)idx * 3;
    const float c0 = cs[0], c1 = cs[1], c2 = cs[2];
    const float xv = xm[idx];
    const float* w = conv_w + c * 4;
    const float conv = c0 * w[0] + c1 * w[1] + c2 * w[2] + xv * w[3] + conv_b[c];
    xmc[idx] = silu(conv);
    float* no = ncs_out + (size_t)idx * 3;
    no[0] = c1; no[1] = c2; no[2] = xv;
}

// ---------------------------------------------------------------------------
// Gates + per-(b,h) scalars + norm_new + qn + denom. One block per (b,h).
// ---------------------------------------------------------------------------
__global__ void k_gates(const float* __restrict__ qkv, const float* __restrict__ Wi,
                        const float* __restrict__ bi, const float* __restrict__ Wf,
                        const float* __restrict__ bfv, const float* __restrict__ max_state,
                        const float* __restrict__ norm_state,
                        float* __restrict__ ig_ws, float* __restrict__ fg_ws,
                        float* __restrict__ max_new, float* __restrict__ norm_out,
                        float* __restrict__ denom_ws) {
    const int bh = blockIdx.x, b = bh >> 3, h = bh & 7, t = threadIdx.x;
    const float* q  = qkv + (size_t)b * (3 * INNER_);
    const float* wi = Wi + (size_t)h * (3 * INNER_);
    const float* wf = Wf + (size_t)h * (3 * INNER_);
    float si = 0.f, sf = 0.f;
    for (int j = t; j < 3 * INNER_; j += 256) {
        const float v = q[j];
        si += v * wi[j];
        sf += v * wf[j];
    }
    __shared__ float r1[4], r2[4], sc[3];
    for (int off = 32; off; off >>= 1) {
        si += __shfl_down(si, off, 64);
        sf += __shfl_down(sf, off, 64);
    }
    if ((t & 63) == 0) { r1[t >> 6] = si; r2[t >> 6] = sf; }
    __syncthreads();
    if (t == 0) {
        float ig = r1[0] + r1[1] + r1[2] + r1[3] + bi[h];
        float fg = r2[0] + r2[1] + r2[2] + r2[3] + bfv[h];
        ig = CAP_ * tanhf(ig / CAP_);
        fg = CAP_ * tanhf(fg / CAP_);
        const float logf_ = (fg >= 0.f) ? -log1pf(expf(-fg)) : (fg - log1pf(expf(fg)));
        const float ms = max_state[bh];
        const float mn = fmaxf(ig, ms + logf_);
        const float i_g = expf(ig - mn);
        const float f_g = expf(logf_ + ms - mn);
        max_new[bh] = mn; ig_ws[bh] = i_g; fg_ws[bh] = f_g;
        sc[0] = i_g; sc[1] = f_g; sc[2] = mn;
    }
    __syncthreads();
    const float i_g = sc[0], f_g = sc[1], mx = sc[2];
    const float rs = 0.044194173824159216f;   // 1/sqrt(512)
    const float* qr = q + h * HEAD_;
    const float* kr = qr + INNER_;
    const float* ns = norm_state + (size_t)bh * HEAD_;
    float qn = 0.f;
    for (int d = t; d < HEAD_; d += 256) {
        const float qv = qr[d];
        const float nn = f_g * ns[d] + i_g * (kr[d] * rs);
        norm_out[(size_t)bh * HEAD_ + d] = nn;
        qn += qv * nn;
    }
    for (int off = 32; off; off >>= 1) qn += __shfl_down(qn, off, 64);
    if ((t & 63) == 0) r1[t >> 6] = qn;
    __syncthreads();
    if (t == 0) {
        const float q_total = r1[0] + r1[1] + r1[2] + r1[3];
        denom_ws[bh] = fmaxf(fabsf(q_total), expf(-mx)) + 1e-6f;
    }
}

// ---------------------------------------------------------------------------
// Streaming cell update + partial numer. Grid = B*NH*8 (64 d-rows per block).
// ---------------------------------------------------------------------------
__global__ __launch_bounds__(256) void k_cell(const float* __restrict__ qkv,
                       const float* __restrict__ ig_ws, const float* __restrict__ fg_ws,
                       const float* __restrict__ cell_state,
                       float* __restrict__ cell_out, float* __restrict__ numer_ws) {
    const int blk = blockIdx.x;
    const int bh = blk >> 3, chunk = blk & 7;
    const int b = bh >> 3, h = bh & 7, t = threadIdx.x;
    const int d0 = chunk * DCH_;
    __shared__ float q_l[DCH_], ik_l[DCH_];
    __shared__ float nred[HEAD_];
    const float i_g = ig_ws[bh], f_g = fg_ws[bh];
    const float rs = 0.044194173824159216f;
    const float* qr = qkv + (size_t)b * (3 * INNER_) + h * HEAD_;
    const float* kr = qr + INNER_;
    const float* vr = qr + 2 * INNER_;
    if (t < DCH_) {
        q_l[t]  = qr[d0 + t];
        ik_l[t] = i_g * (kr[d0 + t] * rs);
    }
    __syncthreads();
    const int half = t >> 7;
    const int col  = (t & 127) * 4;
    const float4 v4 = *(const float4*)(vr + col);
    const float* pin  = cell_state + (size_t)bh * HEAD_ * HEAD_ + (size_t)(d0 + half) * HEAD_ + col;
    float*       pout = cell_out   + (size_t)bh * HEAD_ * HEAD_ + (size_t)(d0 + half) * HEAD_ + col;
    float4 num = {0.f, 0.f, 0.f, 0.f};
    #pragma unroll 4
    for (int it = 0; it < DCH_ / 2; ++it) {
        const int d = it * 2 + half;
        const float4 c4 = *(const float4*)pin;
        const float ik = ik_l[d], qv = q_l[d];
        float4 cn;
        cn.x = f_g * c4.x + ik * v4.x;
        cn.y = f_g * c4.y + ik * v4.y;
        cn.z = f_g * c4.z + ik * v4.z;
        cn.w = f_g * c4.w + ik * v4.w;
        *(float4*)pout = cn;
        num.x += qv * cn.x; num.y += qv * cn.y; num.z += qv * cn.z; num.w += qv * cn.w;
        pin  += 2 * HEAD_;
        pout += 2 * HEAD_;
    }
    if (half == 0) {
        nred[col] = num.x; nred[col+1] = num.y; nred[col+2] = num.z; nred[col+3] = num.w;
    }
    __syncthreads();
    if (half == 1) {
        float* nw = numer_ws + (size_t)bh * HEAD_;
        atomicAdd(&nw[col],     nred[col]     + num.x);
        atomicAdd(&nw[col + 1], nred[col + 1] + num.y);
        atomicAdd(&nw[col + 2], nred[col + 2] + num.z);
        atomicAdd(&nw[col + 3], nred[col + 3] + num.w);
    }
}

// ---------------------------------------------------------------------------
// Epilogue: groupnorm over HEAD + skip + gate -> h. One block per (b,h).
// ---------------------------------------------------------------------------
__global__ void k_epi(const float* __restrict__ numer_ws, const float* __restrict__ denom_ws,
                      const float* __restrict__ gn_w, const float* __restrict__ gn_b,
                      const float* __restrict__ skip_w, const float* __restrict__ xmc,
                      const float* __restrict__ x_gate, float* __restrict__ h_out) {
    const int bh = blockIdx.x, b = bh >> 3, h = bh & 7, t = threadIdx.x;
    __shared__ float redA[4], redB[4];
    const float denom = denom_ws[bh];
    const float* nu = numer_ws + (size_t)bh * HEAD_;
    float s = 0.f, s2 = 0.f;
    for (int e = t; e < HEAD_; e += 256) {
        const float o = nu[e] / denom;
        s += o; s2 += o * o;
    }
    for (int off = 32; off; off >>= 1) {
        s  += __shfl_down(s, off, 64);
        s2 += __shfl_down(s2, off, 64);
    }
    if ((t & 63) == 0) { redA[t >> 6] = s; redB[t >> 6] = s2; }
    __syncthreads();
    const float mu  = (redA[0] + redA[1] + redA[2] + redA[3]) / (float)HEAD_;
    const float ex2 = (redB[0] + redB[1] + redB[2] + redB[3]) / (float)HEAD_;
    const float inv = rsqrtf(fmaxf(ex2 - mu * mu, 0.f) + 1e-5f);
    for (int e = t; e < HEAD_; e += 256) {
        const int i = h * HEAD_ + e;
        const float og = (nu[e] / denom - mu) * inv * gn_w[i] + gn_b[i];
        const float xg = x_gate[(size_t)b * INNER_ + i];
        const float hv = (og + skip_w[i] * xmc[(size_t)b * INNER_ + i]) * silu(xg);
        h_out[(size_t)b * INNER_ + i] = hv;
    }
}

// ---------------------------------------------------------------------------
extern "C" void kernel_launch(void* const* d_in, const int* in_sizes, int n_in,
                              void* d_out, int out_size, void* d_ws, size_t ws_size,
                              hipStream_t stream) {
    const float* x          = (const float*)d_in[0];
    const float* conv_state = (const float*)d_in[1];
    const float* cell_state = (const float*)d_in[2];
    const float* norm_state = (const float*)d_in[3];
    const float* max_state  = (const float*)d_in[4];
    const float* rms_w      = (const float*)d_in[5];
    const float* Wx         = (const float*)d_in[6];
    const float* Wg         = (const float*)d_in[7];
    const float* Wqkv       = (const float*)d_in[8];
    const float* conv_w     = (const float*)d_in[9];
    const float* conv_b     = (const float*)d_in[10];
    const float* Wi         = (const float*)d_in[11];
    const float* bi         = (const float*)d_in[12];
    const float* Wf         = (const float*)d_in[13];
    const float* bfv        = (const float*)d_in[14];
    const float* gn_w       = (const float*)d_in[15];
    const float* gn_b       = (const float*)d_in[16];
    const float* Wdown      = (const float*)d_in[17];
    const float* skip_w     = (const float*)d_in[18];

    float* out = (float*)d_out;
    float* y_out    = out;                                   // 32*2048
    float* ncs_out  = y_out + B_ * HID_;                     // 32*4096*3
    float* cell_out = ncs_out + (size_t)B_ * INNER_ * 3;     // 32*8*512*512
    float* norm_out = cell_out + (size_t)B_ * NH_ * HEAD_ * HEAD_;
    float* max_out  = norm_out + (size_t)B_ * NH_ * HEAD_;

    float* w = (float*)d_ws;
    float* xn       = w;                          // 65536
    float* xmc      = xn + B_ * HID_;             // 131072
    float* h_ws     = xmc + B_ * INNER_;          // 131072
    float* ig_ws    = h_ws + B_ * INNER_;         // 256
    float* fg_ws    = ig_ws + B_ * NH_;           // 256
    float* denom_ws = fg_ws + B_ * NH_;           // 256
    float* x_mlstm  = denom_ws + B_ * NH_;        // 131072  (zeroed)
    float* x_gate   = x_mlstm + B_ * INNER_;      // 131072  (zeroed)
    float* qkv      = x_gate + B_ * INNER_;       // 393216  (zeroed)
    float* numer_ws = qkv + B_ * 3 * INNER_;      // 131072  (zeroed)

    // zero the atomic targets (x_mlstm, x_gate, qkv, numer_ws contiguous)
    hipMemsetAsync(x_mlstm, 0,
                   (size_t)(2 * B_ * INNER_ + B_ * 3 * INNER_ + B_ * NH_ * HEAD_) * 4, stream);
    hipMemcpyAsync(y_out, x, (size_t)B_ * HID_ * 4, hipMemcpyDeviceToDevice, stream);

    k_rms<<<B_, 256, 0, stream>>>(x, rms_w, xn);

    k_gemm<<<dim3(INNER_ / 64, 8), 256, 0, stream>>>(xn, Wx, x_mlstm, INNER_, HID_, HID_ / 8);
    k_gemm<<<dim3(INNER_ / 64, 8), 256, 0, stream>>>(xn, Wg, x_gate, INNER_, HID_, HID_ / 8);

    k_conv<<<(B_ * INNER_) / 256, 256, 0, stream>>>(x_mlstm, conv_state, conv_w, conv_b,
                                                    xmc, ncs_out);

    k_gemm<<<dim3(3 * INNER_ / 64, 8), 256, 0, stream>>>(xmc, Wqkv, qkv,
                                                         3 * INNER_, INNER_, INNER_ / 8);

    k_gates<<<B_ * NH_, 256, 0, stream>>>(qkv, Wi, bi, Wf, bfv, max_state, norm_state,
                                          ig_ws, fg_ws, max_out, norm_out, denom_ws);

    k_cell<<<B_ * NH_ * 8, 256, 0, stream>>>(qkv, ig_ws, fg_ws, cell_state,
                                             cell_out, numer_ws);

    k_epi<<<B_ * NH_, 256, 0, stream>>>(numer_ws, denom_ws, gn_w, gn_b, skip_w,
                                        xmc, x_gate, h_ws);

    k_gemm<<<dim3(HID_ / 64, 16), 256, 0, stream>>>(h_ws, Wdown, y_out, HID_, INNER_, INNER_ / 16);
}